// Round 1
// baseline (16864.703 us; speedup 1.0000x reference)
//
#include <hip/hip_runtime.h>

#define T_LEN 16384

__device__ __forceinline__ float fast_exp2(float x) { return __builtin_amdgcn_exp2f(x); }
__device__ __forceinline__ float fast_rcp(float x)  { return __builtin_amdgcn_rcpf(x); }
// tanh(x) = 1 - 2/(exp2(x*2*log2e)+1) ; sigmoid(x) = 1/(1+exp2(-x*log2e))
__device__ __forceinline__ float fast_tanh(float x) {
  return 1.f - 2.f * fast_rcp(1.f + fast_exp2(x * 2.885390081777927f));
}
__device__ __forceinline__ float fast_sig(float x) {
  return fast_rcp(1.f + fast_exp2(-x * 1.4426950408889634f));
}

// ---------------- input projection 256->32, h layout [B][T][32], zero skip ----
__global__ __launch_bounds__(256, 2) void in_k(
    const float* __restrict__ x, const float* __restrict__ w,
    const float* __restrict__ bias, float* __restrict__ h, float* __restrict__ skip)
{
  __shared__ float4 W[256][8];   // [c][o4] = w[(o4*4+j)*256 + c]
  __shared__ float B[32];
  const int tid = threadIdx.x;
  for (int i = tid; i < 2048; i += 256) {
    int c = i >> 3, o4 = i & 7;
    W[c][o4] = make_float4(w[(o4*4+0)*256 + c], w[(o4*4+1)*256 + c],
                           w[(o4*4+2)*256 + c], w[(o4*4+3)*256 + c]);
  }
  if (tid < 32) B[tid] = bias[tid];
  __syncthreads();

  const int idx = blockIdx.x * 256 + tid;       // 0 .. 131071
  const int b = idx >> 14;
  const int t = idx & (T_LEN - 1);
  const float* xb = x + (size_t)b * 256 * T_LEN + t;

  float acc[32];
  #pragma unroll
  for (int o = 0; o < 32; o++) acc[o] = B[o];
  #pragma unroll 4
  for (int c = 0; c < 256; c++) {
    float v = xb[(size_t)c * T_LEN];
    #pragma unroll
    for (int o4 = 0; o4 < 8; o4++) {
      float4 ww = W[c][o4];
      acc[o4*4+0] += ww.x * v; acc[o4*4+1] += ww.y * v;
      acc[o4*4+2] += ww.z * v; acc[o4*4+3] += ww.w * v;
    }
  }
  float4* hp = (float4*)h + (size_t)idx * 8;
  float4* sp = (float4*)skip + (size_t)idx * 8;
  #pragma unroll
  for (int j = 0; j < 8; j++) {
    hp[j] = make_float4(acc[j*4+0], acc[j*4+1], acc[j*4+2], acc[j*4+3]);
    sp[j] = make_float4(0.f, 0.f, 0.f, 0.f);
  }
}

// ---------------- one residual layer: dconv+gate -> tanh*sig -> res + skip ----
__global__ __launch_bounds__(256, 2) void layer_k(
    const float* __restrict__ hin, float* __restrict__ hout, float* __restrict__ skip,
    const float* __restrict__ cw, const float* __restrict__ cb,
    const float* __restrict__ gw, const float* __restrict__ gb,
    const float* __restrict__ rw, const float* __restrict__ rb,
    const float* __restrict__ sw, const float* __restrict__ sb, int d)
{
  __shared__ float4 WCG[32][32];  // [ic][o] = (wc0, wc1, wg0, wg1)
  __shared__ float2 WRS[32][32];  // [ic][o] = (wr, ws)
  __shared__ float BC[32], BG[32], BR[32], BS[32];
  const int tid = threadIdx.x;
  for (int i = tid; i < 1024; i += 256) {
    int o = i >> 5, ic = i & 31;
    int q = (o * 32 + ic) * 2;
    WCG[ic][o] = make_float4(cw[q], cw[q+1], gw[q], gw[q+1]);
    WRS[ic][o] = make_float2(rw[o*32+ic], sw[o*32+ic]);
  }
  if (tid < 32) { BC[tid]=cb[tid]; BG[tid]=gb[tid]; BR[tid]=rb[tid]; BS[tid]=sb[tid]; }
  __syncthreads();

  const int idx = blockIdx.x * 256 + tid;
  const int t = idx & (T_LEN - 1);

  const float4* hp = (const float4*)hin + (size_t)idx * 8;
  float ht[32], htd[32];
  #pragma unroll
  for (int j = 0; j < 8; j++) {
    float4 v = hp[j];
    ht[j*4+0]=v.x; ht[j*4+1]=v.y; ht[j*4+2]=v.z; ht[j*4+3]=v.w;
  }
  if (t >= d) {
    const float4* hq = hp - (size_t)d * 8;
    #pragma unroll
    for (int j = 0; j < 8; j++) {
      float4 v = hq[j];
      htd[j*4+0]=v.x; htd[j*4+1]=v.y; htd[j*4+2]=v.z; htd[j*4+3]=v.w;
    }
  } else {
    #pragma unroll
    for (int j = 0; j < 32; j++) htd[j] = 0.f;
  }

  float p[32], g[32];
  #pragma unroll
  for (int o = 0; o < 32; o++) { p[o] = BC[o]; g[o] = BG[o]; }
  #pragma unroll
  for (int ic = 0; ic < 32; ic++) {
    float a0 = htd[ic], a1 = ht[ic];
    #pragma unroll
    for (int o = 0; o < 32; o++) {
      float4 w = WCG[ic][o];
      p[o] += w.x * a0 + w.y * a1;
      g[o] += w.z * a0 + w.w * a1;
    }
  }

  float a[32];
  #pragma unroll
  for (int o = 0; o < 32; o++) a[o] = fast_tanh(p[o]) * fast_sig(g[o]);

  float hn[32], sk[32];
  #pragma unroll
  for (int o = 0; o < 32; o++) { hn[o] = ht[o] + BR[o]; sk[o] = BS[o]; }
  #pragma unroll
  for (int ic = 0; ic < 32; ic++) {
    float v = a[ic];
    #pragma unroll
    for (int o = 0; o < 32; o++) {
      float2 w = WRS[ic][o];
      hn[o] += w.x * v;
      sk[o] += w.y * v;
    }
  }

  float4* ho = (float4*)hout + (size_t)idx * 8;
  float4* sp = (float4*)skip + (size_t)idx * 8;
  #pragma unroll
  for (int j = 0; j < 8; j++) {
    ho[j] = make_float4(hn[j*4+0], hn[j*4+1], hn[j*4+2], hn[j*4+3]);
    float4 s = sp[j];
    s.x += sk[j*4+0]; s.y += sk[j*4+1]; s.z += sk[j*4+2]; s.w += sk[j*4+3];
    sp[j] = s;
  }
}

// ---------------- out: relu(W1 @ skip + b1) -> W2 @ . + b2, out [B][256][T] ---
__global__ __launch_bounds__(256, 2) void out_k(
    const float* __restrict__ skip,
    const float* __restrict__ w1, const float* __restrict__ b1,
    const float* __restrict__ w2, const float* __restrict__ b2,
    float* __restrict__ out)
{
  __shared__ float4 W1[32][8];    // [ic][o4]
  __shared__ float4 W2[32][64];   // [ic][o4]
  __shared__ float B1[32];
  __shared__ float B2[256];
  const int tid = threadIdx.x;
  {
    int ic = tid >> 3, o4 = tid & 7;
    W1[ic][o4] = make_float4(w1[(o4*4+0)*32+ic], w1[(o4*4+1)*32+ic],
                             w1[(o4*4+2)*32+ic], w1[(o4*4+3)*32+ic]);
  }
  for (int e = tid; e < 2048; e += 256) {
    int ic = e >> 6, o4 = e & 63;
    W2[ic][o4] = make_float4(w2[(o4*4+0)*32+ic], w2[(o4*4+1)*32+ic],
                             w2[(o4*4+2)*32+ic], w2[(o4*4+3)*32+ic]);
  }
  B2[tid & 255] = b2[tid & 255];
  if (tid < 32) B1[tid] = b1[tid];
  __syncthreads();

  const int idx = blockIdx.x * 256 + tid;
  const int b = idx >> 14;
  const int t = idx & (T_LEN - 1);

  const float4* sp = (const float4*)skip + (size_t)idx * 8;
  float sk[32];
  #pragma unroll
  for (int j = 0; j < 8; j++) {
    float4 v = sp[j];
    sk[j*4+0]=v.x; sk[j*4+1]=v.y; sk[j*4+2]=v.z; sk[j*4+3]=v.w;
  }

  float r[32];
  #pragma unroll
  for (int o = 0; o < 32; o++) r[o] = B1[o];
  #pragma unroll
  for (int ic = 0; ic < 32; ic++) {
    float v = sk[ic];
    #pragma unroll
    for (int o4 = 0; o4 < 8; o4++) {
      float4 w = W1[ic][o4];
      r[o4*4+0] += w.x * v; r[o4*4+1] += w.y * v;
      r[o4*4+2] += w.z * v; r[o4*4+3] += w.w * v;
    }
  }
  #pragma unroll
  for (int o = 0; o < 32; o++) r[o] = fmaxf(r[o], 0.f);

  float* ob = out + (size_t)b * 256 * T_LEN + t;
  #pragma unroll 2
  for (int o4 = 0; o4 < 64; o4++) {
    float a0 = B2[o4*4+0], a1 = B2[o4*4+1], a2 = B2[o4*4+2], a3 = B2[o4*4+3];
    #pragma unroll
    for (int ic = 0; ic < 32; ic++) {
      float4 w = W2[ic][o4];
      float v = r[ic];
      a0 += w.x * v; a1 += w.y * v; a2 += w.z * v; a3 += w.w * v;
    }
    ob[(size_t)(o4*4+0)*T_LEN] = a0;
    ob[(size_t)(o4*4+1)*T_LEN] = a1;
    ob[(size_t)(o4*4+2)*T_LEN] = a2;
    ob[(size_t)(o4*4+3)*T_LEN] = a3;
  }
}

extern "C" void kernel_launch(void* const* d_in, const int* in_sizes, int n_in,
                              void* d_out, int out_size, void* d_ws, size_t ws_size,
                              hipStream_t stream)
{
  const float* x    = (const float*)d_in[0];
  const float* in_w = (const float*)d_in[1];
  const float* in_b = (const float*)d_in[2];
  const float* cw   = (const float*)d_in[3];
  const float* cb   = (const float*)d_in[4];
  const float* gw   = (const float*)d_in[5];
  const float* gb   = (const float*)d_in[6];
  const float* rw   = (const float*)d_in[7];
  const float* rb   = (const float*)d_in[8];
  const float* sw   = (const float*)d_in[9];
  const float* sb   = (const float*)d_in[10];
  const float* w1   = (const float*)d_in[11];
  const float* b1   = (const float*)d_in[12];
  const float* w2   = (const float*)d_in[13];
  const float* b2   = (const float*)d_in[14];
  float* out = (float*)d_out;

  // h ping-pong buffers live in d_out scratch space (first 32 MB of 128 MB);
  // fully overwritten by out_k at the end. skip_sum lives in d_ws (16 MB).
  float* h0   = out;                 // [8][16384][32] = 4,194,304 floats
  float* h1   = out + 4194304;
  float* skip = (float*)d_ws;        // 4,194,304 floats

  dim3 grid(512), blk(256);
  in_k<<<grid, blk, 0, stream>>>(x, in_w, in_b, h0, skip);

  float* ha = h0;
  float* hb = h1;
  for (int l = 0; l < 40; l++) {
    int d = 1 << (l % 10);
    layer_k<<<grid, blk, 0, stream>>>(ha, hb, skip,
        cw + (size_t)l * 2048, cb + l * 32,
        gw + (size_t)l * 2048, gb + l * 32,
        rw + (size_t)l * 1024, rb + l * 32,
        sw + (size_t)l * 1024, sb + l * 32, d);
    float* tmp = ha; ha = hb; hb = tmp;
  }

  out_k<<<grid, blk, 0, stream>>>(skip, w1, b1, w2, b2, out);
}

// Round 2
// 14922.597 us; speedup vs baseline: 1.1301x; 1.1301x over previous
//
#include <hip/hip_runtime.h>

#define T_LEN 16384

__device__ __forceinline__ float fast_exp2(float x) { return __builtin_amdgcn_exp2f(x); }
__device__ __forceinline__ float fast_rcp(float x)  { return __builtin_amdgcn_rcpf(x); }
__device__ __forceinline__ float fast_tanh(float x) {
  return 1.f - 2.f * fast_rcp(1.f + fast_exp2(x * 2.885390081777927f));
}
__device__ __forceinline__ float fast_sig(float x) {
  return fast_rcp(1.f + fast_exp2(-x * 1.4426950408889634f));
}

// h/skip global layout: float4 index ((b*8 + j) * T_LEN + t), j = channel quad.
// Per-thread (one t each) accesses are lane-consecutive 16B -> fully coalesced.

// ---------------- input projection 256->32 ----------------
__global__ __launch_bounds__(256, 4) void in_k(
    const float* __restrict__ x, const float* __restrict__ w,
    const float* __restrict__ bias, float4* __restrict__ h, float4* __restrict__ skip)
{
  __shared__ float4 W[256][8];   // [c][o4] = w[(o4*4+j)*256 + c]
  __shared__ float B[32];
  const int tid = threadIdx.x;
  for (int i = tid; i < 2048; i += 256) {
    int c = i >> 3, o4 = i & 7;
    W[c][o4] = make_float4(w[(o4*4+0)*256 + c], w[(o4*4+1)*256 + c],
                           w[(o4*4+2)*256 + c], w[(o4*4+3)*256 + c]);
  }
  if (tid < 32) B[tid] = bias[tid];
  __syncthreads();

  const int idx = blockIdx.x * 256 + tid;       // 0 .. 131071
  const int b = idx >> 14;
  const int t = idx & (T_LEN - 1);
  const float* xb = x + (size_t)b * 256 * T_LEN + t;

  float acc[32];
  #pragma unroll
  for (int o = 0; o < 32; o++) acc[o] = B[o];
  #pragma unroll 4
  for (int c = 0; c < 256; c++) {
    float v = xb[(size_t)c * T_LEN];
    #pragma unroll
    for (int o4 = 0; o4 < 8; o4++) {
      float4 ww = W[c][o4];
      acc[o4*4+0] += ww.x * v; acc[o4*4+1] += ww.y * v;
      acc[o4*4+2] += ww.z * v; acc[o4*4+3] += ww.w * v;
    }
  }
  #pragma unroll
  for (int j = 0; j < 8; j++) {
    size_t p = ((size_t)(b * 8 + j) << 14) + t;
    h[p]    = make_float4(acc[j*4+0], acc[j*4+1], acc[j*4+2], acc[j*4+3]);
    skip[p] = make_float4(0.f, 0.f, 0.f, 0.f);
  }
}

// ---------------- one residual layer ----------------
__global__ __launch_bounds__(256, 4) void layer_k(
    const float4* __restrict__ hin, float4* __restrict__ hout, float4* __restrict__ skip,
    const float* __restrict__ cw, const float* __restrict__ cb,
    const float* __restrict__ gw, const float* __restrict__ gb,
    const float* __restrict__ rw, const float* __restrict__ rb,
    const float* __restrict__ sw, const float* __restrict__ sb, int d)
{
  __shared__ float4 WCG[32][32];  // [ic][o] = (wc0, wc1, wg0, wg1)
  __shared__ float2 WRS[32][32];  // [ic][o] = (wr, ws)
  __shared__ float BC[32], BG[32], BR[32], BS[32];
  const int tid = threadIdx.x;
  for (int i = tid; i < 1024; i += 256) {
    int o = i >> 5, ic = i & 31;
    int q = (o * 32 + ic) * 2;
    WCG[ic][o] = make_float4(cw[q], cw[q+1], gw[q], gw[q+1]);
    WRS[ic][o] = make_float2(rw[o*32+ic], sw[o*32+ic]);
  }
  if (tid < 32) { BC[tid]=cb[tid]; BG[tid]=gb[tid]; BR[tid]=rb[tid]; BS[tid]=sb[tid]; }
  __syncthreads();

  const int idx = blockIdx.x * 256 + tid;
  const int b = idx >> 14;
  const int t = idx & (T_LEN - 1);
  const size_t base = ((size_t)b * 8 << 14) + t;   // + j*T_LEN

  float ht[32], htd[32];
  #pragma unroll
  for (int j = 0; j < 8; j++) {
    float4 v = hin[base + ((size_t)j << 14)];
    ht[j*4+0]=v.x; ht[j*4+1]=v.y; ht[j*4+2]=v.z; ht[j*4+3]=v.w;
  }
  if (t >= d) {
    #pragma unroll
    for (int j = 0; j < 8; j++) {
      float4 v = hin[base + ((size_t)j << 14) - d];
      htd[j*4+0]=v.x; htd[j*4+1]=v.y; htd[j*4+2]=v.z; htd[j*4+3]=v.w;
    }
  } else {
    #pragma unroll
    for (int j = 0; j < 32; j++) htd[j] = 0.f;
  }

  float p[32], g[32];
  #pragma unroll
  for (int o = 0; o < 32; o++) { p[o] = BC[o]; g[o] = BG[o]; }
  #pragma unroll
  for (int ic = 0; ic < 32; ic++) {
    float a0 = htd[ic], a1 = ht[ic];
    #pragma unroll
    for (int o = 0; o < 32; o++) {
      float4 w = WCG[ic][o];
      p[o] += w.x * a0 + w.y * a1;
      g[o] += w.z * a0 + w.w * a1;
    }
  }

  float a[32];
  #pragma unroll
  for (int o = 0; o < 32; o++) a[o] = fast_tanh(p[o]) * fast_sig(g[o]);

  float hn[32], sk[32];
  #pragma unroll
  for (int o = 0; o < 32; o++) { hn[o] = ht[o] + BR[o]; sk[o] = BS[o]; }
  #pragma unroll
  for (int ic = 0; ic < 32; ic++) {
    float v = a[ic];
    #pragma unroll
    for (int o = 0; o < 32; o++) {
      float2 w = WRS[ic][o];
      hn[o] += w.x * v;
      sk[o] += w.y * v;
    }
  }

  #pragma unroll
  for (int j = 0; j < 8; j++) {
    size_t p4 = base + ((size_t)j << 14);
    hout[p4] = make_float4(hn[j*4+0], hn[j*4+1], hn[j*4+2], hn[j*4+3]);
    float4 s = skip[p4];
    s.x += sk[j*4+0]; s.y += sk[j*4+1]; s.z += sk[j*4+2]; s.w += sk[j*4+3];
    skip[p4] = s;
  }
}

// ---------------- out: relu(W1 @ skip + b1) -> W2 @ . + b2 ----------------
__global__ __launch_bounds__(256, 4) void out_k(
    const float4* __restrict__ skip,
    const float* __restrict__ w1, const float* __restrict__ b1,
    const float* __restrict__ w2, const float* __restrict__ b2,
    float* __restrict__ out)
{
  __shared__ float4 W1[32][8];    // [ic][o4]
  __shared__ float4 W2[32][64];   // [ic][o4]
  __shared__ float B1[32];
  __shared__ float B2[256];
  const int tid = threadIdx.x;
  {
    int ic = tid >> 3, o4 = tid & 7;
    W1[ic][o4] = make_float4(w1[(o4*4+0)*32+ic], w1[(o4*4+1)*32+ic],
                             w1[(o4*4+2)*32+ic], w1[(o4*4+3)*32+ic]);
  }
  for (int e = tid; e < 2048; e += 256) {
    int ic = e >> 6, o4 = e & 63;
    W2[ic][o4] = make_float4(w2[(o4*4+0)*32+ic], w2[(o4*4+1)*32+ic],
                             w2[(o4*4+2)*32+ic], w2[(o4*4+3)*32+ic]);
  }
  B2[tid & 255] = b2[tid & 255];
  if (tid < 32) B1[tid] = b1[tid];
  __syncthreads();

  const int idx = blockIdx.x * 256 + tid;
  const int b = idx >> 14;
  const int t = idx & (T_LEN - 1);
  const size_t base = ((size_t)b * 8 << 14) + t;

  float sk[32];
  #pragma unroll
  for (int j = 0; j < 8; j++) {
    float4 v = skip[base + ((size_t)j << 14)];
    sk[j*4+0]=v.x; sk[j*4+1]=v.y; sk[j*4+2]=v.z; sk[j*4+3]=v.w;
  }

  float r[32];
  #pragma unroll
  for (int o = 0; o < 32; o++) r[o] = B1[o];
  #pragma unroll
  for (int ic = 0; ic < 32; ic++) {
    float v = sk[ic];
    #pragma unroll
    for (int o4 = 0; o4 < 8; o4++) {
      float4 w = W1[ic][o4];
      r[o4*4+0] += w.x * v; r[o4*4+1] += w.y * v;
      r[o4*4+2] += w.z * v; r[o4*4+3] += w.w * v;
    }
  }
  #pragma unroll
  for (int o = 0; o < 32; o++) r[o] = fmaxf(r[o], 0.f);

  float* ob = out + (size_t)b * 256 * T_LEN + t;
  #pragma unroll 2
  for (int o4 = 0; o4 < 64; o4++) {
    float a0 = B2[o4*4+0], a1 = B2[o4*4+1], a2 = B2[o4*4+2], a3 = B2[o4*4+3];
    #pragma unroll
    for (int ic = 0; ic < 32; ic++) {
      float4 w = W2[ic][o4];
      float v = r[ic];
      a0 += w.x * v; a1 += w.y * v; a2 += w.z * v; a3 += w.w * v;
    }
    ob[(size_t)(o4*4+0)*T_LEN] = a0;
    ob[(size_t)(o4*4+1)*T_LEN] = a1;
    ob[(size_t)(o4*4+2)*T_LEN] = a2;
    ob[(size_t)(o4*4+3)*T_LEN] = a3;
  }
}

extern "C" void kernel_launch(void* const* d_in, const int* in_sizes, int n_in,
                              void* d_out, int out_size, void* d_ws, size_t ws_size,
                              hipStream_t stream)
{
  const float* x    = (const float*)d_in[0];
  const float* in_w = (const float*)d_in[1];
  const float* in_b = (const float*)d_in[2];
  const float* cw   = (const float*)d_in[3];
  const float* cb   = (const float*)d_in[4];
  const float* gw   = (const float*)d_in[5];
  const float* gb   = (const float*)d_in[6];
  const float* rw   = (const float*)d_in[7];
  const float* rb   = (const float*)d_in[8];
  const float* sw   = (const float*)d_in[9];
  const float* sb   = (const float*)d_in[10];
  const float* w1   = (const float*)d_in[11];
  const float* b1   = (const float*)d_in[12];
  const float* w2   = (const float*)d_in[13];
  const float* b2   = (const float*)d_in[14];
  float* out = (float*)d_out;

  // h ping-pong (2 x 16 MB) in d_out scratch (overwritten by out_k); skip in d_ws.
  float4* h0   = (float4*)out;               // 1,048,576 float4s each
  float4* h1   = (float4*)(out + 4194304);
  float4* skip = (float4*)d_ws;

  dim3 grid(512), blk(256);
  in_k<<<grid, blk, 0, stream>>>(x, in_w, in_b, h0, skip);

  float4* ha = h0;
  float4* hb = h1;
  for (int l = 0; l < 40; l++) {
    int d = 1 << (l % 10);
    layer_k<<<grid, blk, 0, stream>>>(ha, hb, skip,
        cw + (size_t)l * 2048, cb + l * 32,
        gw + (size_t)l * 2048, gb + l * 32,
        rw + (size_t)l * 1024, rb + l * 32,
        sw + (size_t)l * 1024, sb + l * 32, d);
    float4* tmp = ha; ha = hb; hb = tmp;
  }

  out_k<<<grid, blk, 0, stream>>>(skip, w1, b1, w2, b2, out);
}

// Round 3
// 4205.792 us; speedup vs baseline: 4.0099x; 3.5481x over previous
//
#include <hip/hip_runtime.h>

#define T_LEN 16384

__device__ __forceinline__ float fast_exp2(float x) { return __builtin_amdgcn_exp2f(x); }
__device__ __forceinline__ float fast_rcp(float x)  { return __builtin_amdgcn_rcpf(x); }
__device__ __forceinline__ float fast_tanh(float x) {
  return 1.f - 2.f * fast_rcp(1.f + fast_exp2(x * 2.885390081777927f));
}
__device__ __forceinline__ float fast_sig(float x) {
  return fast_rcp(1.f + fast_exp2(-x * 1.4426950408889634f));
}

// h/skip global layout: float4 index ((b*8 + j) * T_LEN + t), j = channel quad.
// Per-thread (one t each) accesses are lane-consecutive 16B -> fully coalesced.
// NOTE: __launch_bounds__(256,2) everywhere — layer_k live set is ~170 VGPRs;
// capping at 64 (min_waves=4) caused catastrophic scratch spill (R1: 890 MB
// HBM traffic/layer, 14x ideal). Grid is 2 blocks/CU anyway, so no occupancy
// is lost by allowing 256 VGPRs.

// ---------------- input projection 256->32 ----------------
__global__ __launch_bounds__(256, 2) void in_k(
    const float* __restrict__ x, const float* __restrict__ w,
    const float* __restrict__ bias, float4* __restrict__ h, float4* __restrict__ skip)
{
  __shared__ float4 W[256][8];   // [c][o4] = w[(o4*4+j)*256 + c]
  __shared__ float B[32];
  const int tid = threadIdx.x;
  for (int i = tid; i < 2048; i += 256) {
    int c = i >> 3, o4 = i & 7;
    W[c][o4] = make_float4(w[(o4*4+0)*256 + c], w[(o4*4+1)*256 + c],
                           w[(o4*4+2)*256 + c], w[(o4*4+3)*256 + c]);
  }
  if (tid < 32) B[tid] = bias[tid];
  __syncthreads();

  const int idx = blockIdx.x * 256 + tid;       // 0 .. 131071
  const int b = idx >> 14;
  const int t = idx & (T_LEN - 1);
  const float* xb = x + (size_t)b * 256 * T_LEN + t;

  float acc[32];
  #pragma unroll
  for (int o = 0; o < 32; o++) acc[o] = B[o];
  #pragma unroll 4
  for (int c = 0; c < 256; c++) {
    float v = xb[(size_t)c * T_LEN];
    #pragma unroll
    for (int o4 = 0; o4 < 8; o4++) {
      float4 ww = W[c][o4];
      acc[o4*4+0] += ww.x * v; acc[o4*4+1] += ww.y * v;
      acc[o4*4+2] += ww.z * v; acc[o4*4+3] += ww.w * v;
    }
  }
  #pragma unroll
  for (int j = 0; j < 8; j++) {
    size_t p = ((size_t)(b * 8 + j) << 14) + t;
    h[p]    = make_float4(acc[j*4+0], acc[j*4+1], acc[j*4+2], acc[j*4+3]);
    skip[p] = make_float4(0.f, 0.f, 0.f, 0.f);
  }
}

// ---------------- one residual layer ----------------
__global__ __launch_bounds__(256, 2) void layer_k(
    const float4* __restrict__ hin, float4* __restrict__ hout, float4* __restrict__ skip,
    const float* __restrict__ cw, const float* __restrict__ cb,
    const float* __restrict__ gw, const float* __restrict__ gb,
    const float* __restrict__ rw, const float* __restrict__ rb,
    const float* __restrict__ sw, const float* __restrict__ sb, int d)
{
  __shared__ float4 WCG[32][32];  // [ic][o] = (wc0, wc1, wg0, wg1)
  __shared__ float2 WRS[32][32];  // [ic][o] = (wr, ws)
  __shared__ float BC[32], BG[32], BR[32], BS[32];
  const int tid = threadIdx.x;
  // staging: lane-consecutive o -> contiguous LDS writes (conflict-free)
  for (int i = tid; i < 1024; i += 256) {
    int o = i & 31, ic = i >> 5;
    int q = (o * 32 + ic) * 2;
    WCG[ic][o] = make_float4(cw[q], cw[q+1], gw[q], gw[q+1]);
    WRS[ic][o] = make_float2(rw[o*32+ic], sw[o*32+ic]);
  }
  if (tid < 32) { BC[tid]=cb[tid]; BG[tid]=gb[tid]; BR[tid]=rb[tid]; BS[tid]=sb[tid]; }
  __syncthreads();

  const int idx = blockIdx.x * 256 + tid;
  const int b = idx >> 14;
  const int t = idx & (T_LEN - 1);
  const size_t base = ((size_t)b * 8 << 14) + t;   // + j*T_LEN

  float ht[32], htd[32];
  #pragma unroll
  for (int j = 0; j < 8; j++) {
    float4 v = hin[base + ((size_t)j << 14)];
    ht[j*4+0]=v.x; ht[j*4+1]=v.y; ht[j*4+2]=v.z; ht[j*4+3]=v.w;
  }
  if (t >= d) {
    #pragma unroll
    for (int j = 0; j < 8; j++) {
      float4 v = hin[base + ((size_t)j << 14) - d];
      htd[j*4+0]=v.x; htd[j*4+1]=v.y; htd[j*4+2]=v.z; htd[j*4+3]=v.w;
    }
  } else {
    #pragma unroll
    for (int j = 0; j < 32; j++) htd[j] = 0.f;
  }

  float p[32], g[32];
  #pragma unroll
  for (int o = 0; o < 32; o++) { p[o] = BC[o]; g[o] = BG[o]; }
  #pragma unroll
  for (int ic = 0; ic < 32; ic++) {
    float a0 = htd[ic], a1 = ht[ic];
    #pragma unroll
    for (int o = 0; o < 32; o++) {
      float4 w = WCG[ic][o];
      p[o] += w.x * a0 + w.y * a1;
      g[o] += w.z * a0 + w.w * a1;
    }
  }

  float a[32];
  #pragma unroll
  for (int o = 0; o < 32; o++) a[o] = fast_tanh(p[o]) * fast_sig(g[o]);

  float hn[32], sk[32];
  #pragma unroll
  for (int o = 0; o < 32; o++) { hn[o] = ht[o] + BR[o]; sk[o] = BS[o]; }
  #pragma unroll
  for (int ic = 0; ic < 32; ic++) {
    float v = a[ic];
    #pragma unroll
    for (int o = 0; o < 32; o++) {
      float2 w = WRS[ic][o];
      hn[o] += w.x * v;
      sk[o] += w.y * v;
    }
  }

  #pragma unroll
  for (int j = 0; j < 8; j++) {
    size_t p4 = base + ((size_t)j << 14);
    hout[p4] = make_float4(hn[j*4+0], hn[j*4+1], hn[j*4+2], hn[j*4+3]);
    float4 s = skip[p4];
    s.x += sk[j*4+0]; s.y += sk[j*4+1]; s.z += sk[j*4+2]; s.w += sk[j*4+3];
    skip[p4] = s;
  }
}

// ---------------- out: relu(W1 @ skip + b1) -> W2 @ . + b2 ----------------
__global__ __launch_bounds__(256, 2) void out_k(
    const float4* __restrict__ skip,
    const float* __restrict__ w1, const float* __restrict__ b1,
    const float* __restrict__ w2, const float* __restrict__ b2,
    float* __restrict__ out)
{
  __shared__ float4 W1[32][8];    // [ic][o4]
  __shared__ float4 W2[32][64];   // [ic][o4]
  __shared__ float B1[32];
  __shared__ float B2[256];
  const int tid = threadIdx.x;
  {
    int ic = tid >> 3, o4 = tid & 7;
    W1[ic][o4] = make_float4(w1[(o4*4+0)*32+ic], w1[(o4*4+1)*32+ic],
                             w1[(o4*4+2)*32+ic], w1[(o4*4+3)*32+ic]);
  }
  for (int e = tid; e < 2048; e += 256) {
    int ic = e >> 6, o4 = e & 63;
    W2[ic][o4] = make_float4(w2[(o4*4+0)*32+ic], w2[(o4*4+1)*32+ic],
                             w2[(o4*4+2)*32+ic], w2[(o4*4+3)*32+ic]);
  }
  B2[tid & 255] = b2[tid & 255];
  if (tid < 32) B1[tid] = b1[tid];
  __syncthreads();

  const int idx = blockIdx.x * 256 + tid;
  const int b = idx >> 14;
  const int t = idx & (T_LEN - 1);
  const size_t base = ((size_t)b * 8 << 14) + t;

  float sk[32];
  #pragma unroll
  for (int j = 0; j < 8; j++) {
    float4 v = skip[base + ((size_t)j << 14)];
    sk[j*4+0]=v.x; sk[j*4+1]=v.y; sk[j*4+2]=v.z; sk[j*4+3]=v.w;
  }

  float r[32];
  #pragma unroll
  for (int o = 0; o < 32; o++) r[o] = B1[o];
  #pragma unroll
  for (int ic = 0; ic < 32; ic++) {
    float v = sk[ic];
    #pragma unroll
    for (int o4 = 0; o4 < 8; o4++) {
      float4 w = W1[ic][o4];
      r[o4*4+0] += w.x * v; r[o4*4+1] += w.y * v;
      r[o4*4+2] += w.z * v; r[o4*4+3] += w.w * v;
    }
  }
  #pragma unroll
  for (int o = 0; o < 32; o++) r[o] = fmaxf(r[o], 0.f);

  float* ob = out + (size_t)b * 256 * T_LEN + t;
  #pragma unroll 2
  for (int o4 = 0; o4 < 64; o4++) {
    float a0 = B2[o4*4+0], a1 = B2[o4*4+1], a2 = B2[o4*4+2], a3 = B2[o4*4+3];
    #pragma unroll
    for (int ic = 0; ic < 32; ic++) {
      float4 w = W2[ic][o4];
      float v = r[ic];
      a0 += w.x * v; a1 += w.y * v; a2 += w.z * v; a3 += w.w * v;
    }
    ob[(size_t)(o4*4+0)*T_LEN] = a0;
    ob[(size_t)(o4*4+1)*T_LEN] = a1;
    ob[(size_t)(o4*4+2)*T_LEN] = a2;
    ob[(size_t)(o4*4+3)*T_LEN] = a3;
  }
}

extern "C" void kernel_launch(void* const* d_in, const int* in_sizes, int n_in,
                              void* d_out, int out_size, void* d_ws, size_t ws_size,
                              hipStream_t stream)
{
  const float* x    = (const float*)d_in[0];
  const float* in_w = (const float*)d_in[1];
  const float* in_b = (const float*)d_in[2];
  const float* cw   = (const float*)d_in[3];
  const float* cb   = (const float*)d_in[4];
  const float* gw   = (const float*)d_in[5];
  const float* gb   = (const float*)d_in[6];
  const float* rw   = (const float*)d_in[7];
  const float* rb   = (const float*)d_in[8];
  const float* sw   = (const float*)d_in[9];
  const float* sb   = (const float*)d_in[10];
  const float* w1   = (const float*)d_in[11];
  const float* b1   = (const float*)d_in[12];
  const float* w2   = (const float*)d_in[13];
  const float* b2   = (const float*)d_in[14];
  float* out = (float*)d_out;

  // h ping-pong (2 x 16 MB) in d_out scratch (overwritten by out_k); skip in d_ws.
  float4* h0   = (float4*)out;               // 1,048,576 float4s each
  float4* h1   = (float4*)(out + 4194304);
  float4* skip = (float4*)d_ws;

  dim3 grid(512), blk(256);
  in_k<<<grid, blk, 0, stream>>>(x, in_w, in_b, h0, skip);

  float4* ha = h0;
  float4* hb = h1;
  for (int l = 0; l < 40; l++) {
    int d = 1 << (l % 10);
    layer_k<<<grid, blk, 0, stream>>>(ha, hb, skip,
        cw + (size_t)l * 2048, cb + l * 32,
        gw + (size_t)l * 2048, gb + l * 32,
        rw + (size_t)l * 1024, rb + l * 32,
        sw + (size_t)l * 1024, sb + l * 32, d);
    float4* tmp = ha; ha = hb; hb = tmp;
  }

  out_k<<<grid, blk, 0, stream>>>(skip, w1, b1, w2, b2, out);
}